// Round 1
// baseline (549.072 us; speedup 1.0000x reference)
//
#include <hip/hip_runtime.h>
#include <math.h>

#define TSTEPS 512
#define RPB 8
#define L2E  1.4426950408889634f
#define L2E2 2.8853900817779268f   // 2*log2(e)

typedef __attribute__((ext_vector_type(4))) short short4v;
typedef __attribute__((ext_vector_type(8))) short short8;
typedef __attribute__((ext_vector_type(4))) float f32x4;
typedef __bf16 bf16x8 __attribute__((ext_vector_type(8)));

__device__ __forceinline__ short f2bf(float f) {            // RNE float->bf16
    union { float f; unsigned u; } v; v.f = f;
    return (short)((v.u + 0x7FFFu + ((v.u >> 16) & 1u)) >> 16);
}
__device__ __forceinline__ float rcp_f(float x) { return __builtin_amdgcn_rcpf(x); }
__device__ __forceinline__ float ex2(float x)   { return __builtin_amdgcn_exp2f(x); }
__device__ __forceinline__ f32x4 mfma16(bf16x8 a, bf16x8 b, f32x4 c) {
    return __builtin_amdgcn_mfma_f32_16x16x32_bf16(a, b, c, 0, 0, 0);
}
// quad_perm DPP: 0xB1 = lane^1, 0x4E = lane^2 (within each 4-lane quad)
template<int CTRL>
__device__ __forceinline__ float dpp4(float v) {
    return __builtin_bit_cast(float,
        __builtin_amdgcn_mov_dpp(__builtin_bit_cast(int, v), CTRL, 0xF, 0xF, true));
}

// 256 blocks x 512 threads (8 waves -> 2 per SIMD for MFMA/VALU/LDS overlap).
// Same merged 16x16 MFMA tile, K=224 block-diagonal:
//   A rows 0-7  = [x_t (32) | h0^{t-1} (64) | 0 (128)]        -> L0 step t
//   A rows 8-15 = [0 (96)   | h0^{t-1} (64) | h1^{t-2} (64)]  -> L1 step t-1
// Zero A-blocks now live in zero-initialized REGISTERS (lanes n<8 read only
// x/h0-L0 fragments; lanes n>=8 read only h0-L1/h1) -> LDS read bandwidth
// unchanged vs the 4-wave kernel despite 2x waves; zero LDS rows deleted.
// Column mapping is gate-interleaved: tile col n = gate (n&3) of cell
// (4*tile + (n>>2)); each wave owns 2 tiles (cells 8*wl..8*wl+7, all gates).
// Sigmoid gates' weights/bias are scaled by -log2(e), tanh gate by +2log2(e),
// so activation is branch-free: act = A + B*rcp(1+exp2(v)). A 4x4 quad
// transpose (DPP quad_perm) then gives each lane (i,f,g,o) of one (row,cell);
// c stays fp32 in registers (layer by q = lane>>4: q<2 -> L0).
__global__ __launch_bounds__(512, 2)
void lstm_mfma_68547678044465(const float* __restrict__ x,
                              const float* __restrict__ Wih0, const float* __restrict__ Whh0,
                              const float* __restrict__ bih0, const float* __restrict__ bhh0,
                              const float* __restrict__ Wih1, const float* __restrict__ Whh1,
                              const float* __restrict__ bih1, const float* __restrict__ bhh1,
                              const float* __restrict__ ln_g, const float* __restrict__ ln_b,
                              const float* __restrict__ fcw, const float* __restrict__ fcb,
                              float* __restrict__ out)
{
    __shared__ __align__(16) short XB[2][8][8][40];   // x bf16, rows 0-7 only
    __shared__ __align__(16) short HA[2][8][72];      // h0 rows 0-7
    __shared__ __align__(16) short HC[2][8][72];      // h1 rows 0-7
    __shared__ __align__(16) float HF[8][64];         // final h1 fp32 for LN

    const int tid  = threadIdx.x;
    const int wl   = tid >> 6;           // wave 0..7
    const int lane = tid & 63;
    const int n    = lane & 15;          // A row m / C col n
    const int q    = lane >> 4;          // k-quad / C row group
    const int j    = lane & 3;           // lane-in-quad == gate (n&3)
    const int cl   = n >> 2;             // cell-local within tile
    const int gate = n & 3;              // 0=i 1=f 2=g 3=o
    const int rb   = blockIdx.x * RPB;
    const bool s1  = (lane & 1) != 0;
    const bool s2  = (lane & 2) != 0;

    // per-gate folded scale + branch-free activation constants
    const float sc   = (gate == 2) ? L2E2 : -L2E;
    const float actA = (gate == 2) ? 1.0f  : 0.0f;
    const float actB = (gate == 2) ? -2.0f : 1.0f;
    const int   wr0  = gate * 64 + wl * 8 + cl;   // weight row, tile0 cell
    const int   wr1  = wr0 + 4;                   // tile1 cell
    const int   ko   = q * 8;

    auto loadB = [&](const float* wrow) -> bf16x8 {
        const float4 lo = *(const float4*)(wrow);
        const float4 hi = *(const float4*)(wrow + 4);
        short8 r;
        r[0] = f2bf(lo.x * sc); r[1] = f2bf(lo.y * sc);
        r[2] = f2bf(lo.z * sc); r[3] = f2bf(lo.w * sc);
        r[4] = f2bf(hi.x * sc); r[5] = f2bf(hi.y * sc);
        r[6] = f2bf(hi.z * sc); r[7] = f2bf(hi.w * sc);
        return (bf16x8)r;
    };
    const bf16x8 B0_0 = loadB(Wih0 + wr0 * 32 + ko);
    const bf16x8 B0_1 = loadB(Whh0 + wr0 * 64 + ko);
    const bf16x8 B0_2 = loadB(Whh0 + wr0 * 64 + 32 + ko);
    const bf16x8 B0_3 = loadB(Wih1 + wr0 * 64 + ko);
    const bf16x8 B0_4 = loadB(Wih1 + wr0 * 64 + 32 + ko);
    const bf16x8 B0_5 = loadB(Whh1 + wr0 * 64 + ko);
    const bf16x8 B0_6 = loadB(Whh1 + wr0 * 64 + 32 + ko);
    const bf16x8 B1_0 = loadB(Wih0 + wr1 * 32 + ko);
    const bf16x8 B1_1 = loadB(Whh0 + wr1 * 64 + ko);
    const bf16x8 B1_2 = loadB(Whh0 + wr1 * 64 + 32 + ko);
    const bf16x8 B1_3 = loadB(Wih1 + wr1 * 64 + ko);
    const bf16x8 B1_4 = loadB(Wih1 + wr1 * 64 + 32 + ko);
    const bf16x8 B1_5 = loadB(Whh1 + wr1 * 64 + ko);
    const bf16x8 B1_6 = loadB(Whh1 + wr1 * 64 + 32 + ko);

    // biases: per-lane layer select (rows 4q..4q+3 are all L0 iff q<2)
    float b0, b1;
    if (q < 2) { b0 = (bih0[wr0] + bhh0[wr0]) * sc; b1 = (bih0[wr1] + bhh0[wr1]) * sc; }
    else       { b0 = (bih1[wr0] + bhh1[wr0]) * sc; b1 = (bih1[wr1] + bhh1[wr1]) * sc; }

    // zero h parity buffers (h^{-1} = 0); XB fully written before each use
    { int* z = (int*)HA; for (int i = tid; i < 576; i += 512) z[i] = 0; }
    { int* z = (int*)HC; for (int i = tid; i < 576; i += 512) z[i] = 0; }

    // ---- x staging: thread -> (step ss, row sm, float4 k4), 1 float4 each ----
    const int ss = wl, sm = (tid >> 3) & 7, k4 = tid & 7;
    const float* xrow = x + (size_t)(rb + sm) * (TSTEPS * 32);
    float4 xr0 = *(const float4*)(xrow + ss * 32 + k4 * 4);
    auto xstore = [&](int buf) {
        short4v pa; pa[0] = f2bf(xr0.x); pa[1] = f2bf(xr0.y);
        pa[2] = f2bf(xr0.z); pa[3] = f2bf(xr0.w);
        *(short4v*)&XB[buf][ss][sm][k4 * 4] = pa;
    };
    xstore(0);
    __syncthreads();

    const int rlo = (n < 8) ? n : (n - 8);
    const int aH  = rlo * 72 + ko;
    const int aX  = n * 40 + ko;               // only touched when n<8

    short8 z8 = {0, 0, 0, 0, 0, 0, 0, 0};
    bf16x8 a0 = (bf16x8)z8, a1 = a0, a2 = a0, a3 = a0, a4 = a0, a5 = a0, a6 = a0;
    float c0 = 0.0f, c1 = 0.0f;

    // activate own gate (4 rows), 4x4 quad transpose, c/h update for row 4q+j
    auto finishAct = [&](const f32x4& Ac, float& c, bool freeze) -> float {
        float r0 = fmaf(actB, rcp_f(1.0f + ex2(Ac[0])), actA);
        float r1 = fmaf(actB, rcp_f(1.0f + ex2(Ac[1])), actA);
        float r2 = fmaf(actB, rcp_f(1.0f + ex2(Ac[2])), actA);
        float r3 = fmaf(actB, rcp_f(1.0f + ex2(Ac[3])), actA);
        float t0 = s2 ? r0 : r2, t1 = s2 ? r1 : r3;
        float u0 = dpp4<0x4E>(t0), u1 = dpp4<0x4E>(t1);
        float e0 = s2 ? u0 : r0, e1 = s2 ? u1 : r1;
        float e2 = s2 ? r2 : u0, e3 = s2 ? r3 : u1;
        float p0 = s1 ? e0 : e1; float g0 = dpp4<0xB1>(p0);
        float wi = s1 ? g0 : e0;
        float wf = s1 ? e1 : g0;
        float p1 = s1 ? e2 : e3; float g1 = dpp4<0xB1>(p1);
        float wg = s1 ? g1 : e2;
        float wo = s1 ? e3 : g1;
        float cn = fmaf(wf, c, wi * wg);
        c = freeze ? 0.0f : cn;
        float th = fmaf(-2.0f, rcp_f(1.0f + ex2(c * L2E2)), 1.0f);
        return wo * th;                      // exact 0 when frozen
    };

#pragma unroll 1
    for (int it = 0; it <= TSTEPS; ++it) {
        const int p = it & 1;

        if (((it & 7) == 0) && (it + 8 < TSTEPS))          // prefetch next group
            xr0 = *(const float4*)(xrow + (size_t)(it + 8 + ss) * 32 + k4 * 4);

        // ---- A fragments: exec-masked by row group; other frags stay 0 ----
        const short* xb = &XB[(it >> 3) & 1][it & 7][0][0];
        const short* ha = &HA[p][0][0];
        const short* hc = &HC[p][0][0];
        if (n < 8) {
            a0 = *(const bf16x8*)(xb + aX);                // x_t
            a1 = *(const bf16x8*)(ha + aH);                // h0 k 0-31 (L0 rows)
            a2 = *(const bf16x8*)(ha + aH + 32);           // h0 k 32-63
        } else {
            a3 = *(const bf16x8*)(ha + aH);                // h0 k 0-31 (L1 rows)
            a4 = *(const bf16x8*)(ha + aH + 32);           // h0 k 32-63
            a5 = *(const bf16x8*)(hc + aH);                // h1 k 0-31
            a6 = *(const bf16x8*)(hc + aH + 32);           // h1 k 32-63
        }

        f32x4 A0 = {b0, b0, b0, b0}, A1 = {b1, b1, b1, b1};
        A0 = mfma16(a0, B0_0, A0); A1 = mfma16(a0, B1_0, A1);
        A0 = mfma16(a1, B0_1, A0); A1 = mfma16(a1, B1_1, A1);
        A0 = mfma16(a2, B0_2, A0); A1 = mfma16(a2, B1_2, A1);
        A0 = mfma16(a3, B0_3, A0); A1 = mfma16(a3, B1_3, A1);
        A0 = mfma16(a4, B0_4, A0); A1 = mfma16(a4, B1_4, A1);
        A0 = mfma16(a5, B0_5, A0); A1 = mfma16(a5, B1_5, A1);
        A0 = mfma16(a6, B0_6, A0); A1 = mfma16(a6, B1_6, A1);

        // L1 lanes (q>=2) at it==0 would compute phantom step -1: freeze c;
        // frozen h is exactly 0, so the store is harmless (== the zero init).
        const bool freeze = (it == 0) && (q >= 2);
        float hv0 = finishAct(A0, c0, freeze);
        float hv1 = finishAct(A1, c1, freeze);

        // ---- h store into parity p^1 (one (row,cell) per lane per tile) ----
        short* hb = (q < 2) ? &HA[p ^ 1][0][0] : &HC[p ^ 1][0][0];
        const int rg = (q * 4 + j) & 7;          // row within layer 0..7
        const int cell0 = wl * 8 + cl;           // tile0 cell; tile1 = +4
        hb[rg * 72 + cell0]     = f2bf(hv0);
        hb[rg * 72 + cell0 + 4] = f2bf(hv1);
        if ((it == TSTEPS) && (q >= 2)) {        // final h1 (step T-1), fp32
            HF[rg][cell0]     = hv0;
            HF[rg][cell0 + 4] = hv1;
        }

        if (((it & 7) == 6) && (it + 2 < TSTEPS)) xstore(((it >> 3) + 1) & 1);
        __syncthreads();
    }

    // ---- epilogue: LayerNorm + FC; each wave handles 1 row ----
    const float lg = ln_g[lane], lb = ln_b[lane], fw = fcw[lane], fb = fcb[0];
    const float v = HF[wl][lane];
    float s1r = v, sqr = v * v;
#pragma unroll
    for (int mm = 1; mm < 64; mm <<= 1) {
        s1r += __shfl_xor(s1r, mm, 64);
        sqr += __shfl_xor(sqr, mm, 64);
    }
    const float mu = s1r * (1.0f / 64.0f);
    float var = sqr * (1.0f / 64.0f) - mu * mu;
    var = fmaxf(var, 0.0f);
    const float rs = rsqrtf(var + 1e-5f);
    float pv = ((v - mu) * rs * lg + lb) * fw;
#pragma unroll
    for (int mm = 1; mm < 64; mm <<= 1) pv += __shfl_xor(pv, mm, 64);
    if (lane == 0) out[rb + wl] = pv + fb;
}

extern "C" void kernel_launch(void* const* d_in, const int* in_sizes, int n_in,
                              void* d_out, int out_size, void* d_ws, size_t ws_size,
                              hipStream_t stream) {
    const float* x    = (const float*)d_in[0];
    const float* Wih0 = (const float*)d_in[1];
    const float* Whh0 = (const float*)d_in[2];
    const float* bih0 = (const float*)d_in[3];
    const float* bhh0 = (const float*)d_in[4];
    const float* Wih1 = (const float*)d_in[5];
    const float* Whh1 = (const float*)d_in[6];
    const float* bih1 = (const float*)d_in[7];
    const float* bhh1 = (const float*)d_in[8];
    const float* ln_g = (const float*)d_in[9];
    const float* ln_b = (const float*)d_in[10];
    const float* fcw  = (const float*)d_in[11];
    const float* fcb  = (const float*)d_in[12];

    dim3 grid(2048 / RPB);    // 256 blocks -> 1 per CU
    dim3 block(512);          // 8 waves: 2 per SIMD (phase overlap)
    hipLaunchKernelGGL(lstm_mfma_68547678044465, grid, block, 0, stream,
                       x, Wih0, Whh0, bih0, bhh0, Wih1, Whh1, bih1, bhh1,
                       ln_g, ln_b, fcw, fcb, (float*)d_out);
}

// Round 2
// 472.346 us; speedup vs baseline: 1.1624x; 1.1624x over previous
//
#include <hip/hip_runtime.h>
#include <math.h>

#define TSTEPS 512
#define RPB 8
#define L2E  1.4426950408889634f
#define L2E2 2.8853900817779268f   // 2*log2(e)

typedef __attribute__((ext_vector_type(4))) short short4v;
typedef __attribute__((ext_vector_type(8))) short short8;
typedef __attribute__((ext_vector_type(4))) float f32x4;
typedef __bf16 bf16x8 __attribute__((ext_vector_type(8)));

__device__ __forceinline__ short f2bf(float f) {            // RNE float->bf16
    union { float f; unsigned u; } v; v.f = f;
    return (short)((v.u + 0x7FFFu + ((v.u >> 16) & 1u)) >> 16);
}
__device__ __forceinline__ unsigned pkbf(float lo, float hi) {  // HW RNE pack
    unsigned r;
    asm("v_cvt_pk_bf16_f32 %0, %1, %2" : "=v"(r) : "v"(lo), "v"(hi));
    return r;
}
__device__ __forceinline__ float rcp_f(float x) { return __builtin_amdgcn_rcpf(x); }
__device__ __forceinline__ float ex2(float x)   { return __builtin_amdgcn_exp2f(x); }
__device__ __forceinline__ float sigm_p(float v) { return rcp_f(1.0f + ex2(-v)); }   // v = x*log2e
__device__ __forceinline__ float tanh_p(float v) {                                    // v = x*2log2e
    return fmaf(-2.0f, rcp_f(1.0f + ex2(v)), 1.0f);        // 1 - 2/(1+e^{2x})
}
__device__ __forceinline__ f32x4 mfma16(bf16x8 a, bf16x8 b, f32x4 c) {
    return __builtin_amdgcn_mfma_f32_16x16x32_bf16(a, b, c, 0, 0, 0);
}

// 256 blocks x 256 threads (4 waves, 1/SIMD). Both layers merged into ONE
// 16x16 MFMA tile via block-diagonal K-packing (K=224):
//   A rows 0-7  = [x_t (32) | h0^{t-1} (64) | 0 (128)]        -> L0 step t
//   A rows 8-15 = [0 (96)   | h0^{t-1} (64) | h1^{t-2} (64)]  -> L1 step t-1
// This round: the 8-step group is FULLY UNROLLED so every LDS address is a
// per-lane base + compile-time immediate, parity/buffer selects are
// compile-time, the it==0 freeze selects exist only in sub-iter 0, the
// it==TSTEPS epilogue step is peeled, and h->bf16 uses v_cvt_pk_bf16_f32
// (HW RNE, bit-identical to the manual RNE) -> minimal per-iter VALU.
#define ACTK(g0v, g1v, g2v, g3v, cc, hh, FRZ) do {                     \
    const float iv_ = sigm_p(g0v), fv_ = sigm_p(g1v);                  \
    const float gv_ = tanh_p(g2v), ov_ = sigm_p(g3v);                  \
    const float cn_ = fmaf(fv_, cc, iv_ * gv_);                        \
    cc = (FRZ) ? 0.0f : cn_;                                           \
    hh = ov_ * tanh_p(cc * L2E2);                                      \
} while (0)

#define MFMA_ALL7()                                                     \
    A0 = mfma16(a0, B0_0, A0); A1 = mfma16(a0, B1_0, A1);               \
    A2 = mfma16(a0, B2_0, A2); A3 = mfma16(a0, B3_0, A3);               \
    A0 = mfma16(a1, B0_1, A0); A1 = mfma16(a1, B1_1, A1);               \
    A2 = mfma16(a1, B2_1, A2); A3 = mfma16(a1, B3_1, A3);               \
    A0 = mfma16(a2, B0_2, A0); A1 = mfma16(a2, B1_2, A1);               \
    A2 = mfma16(a2, B2_2, A2); A3 = mfma16(a2, B3_2, A3);               \
    A0 = mfma16(a3, B0_3, A0); A1 = mfma16(a3, B1_3, A1);               \
    A2 = mfma16(a3, B2_3, A2); A3 = mfma16(a3, B3_3, A3);               \
    A0 = mfma16(a4, B0_4, A0); A1 = mfma16(a4, B1_4, A1);               \
    A2 = mfma16(a4, B2_4, A2); A3 = mfma16(a4, B3_4, A3);               \
    A0 = mfma16(a5, B0_5, A0); A1 = mfma16(a5, B1_5, A1);               \
    A2 = mfma16(a5, B2_5, A2); A3 = mfma16(a5, B3_5, A3);               \
    A0 = mfma16(a6, B0_6, A0); A1 = mfma16(a6, B1_6, A1);               \
    A2 = mfma16(a6, B2_6, A2); A3 = mfma16(a6, B3_6, A3);

// One timestep. SUB: compile-time 0..7 (parity = SUB&1). PREF/XST: uniform
// runtime bools. FRZ: freeze selects (only sub 0 of group 0 passes non-false).
#define STEPB(SUB, PREF, XST, FRZ) do {                                 \
    if (PREF) {                                                         \
        xr0 = *(const float4*)(xp);                                     \
        xr1 = *(const float4*)(xp + 16);                                \
    }                                                                   \
    const short* haS_ = ((SUB) & 1) ? haB : haA;                        \
    const short* hcS_ = ((SUB) & 1) ? hcB : hcA;                        \
    const bf16x8 a0 = *(const bf16x8*)(xbR + (SUB) * 640);              \
    const bf16x8 a1 = *(const bf16x8*)(haS_ + oH1);                     \
    const bf16x8 a2 = *(const bf16x8*)(haS_ + oH1 + 32);                \
    const bf16x8 a3 = *(const bf16x8*)(haS_ + oH2);                     \
    const bf16x8 a4 = *(const bf16x8*)(haS_ + oH2 + 32);                \
    const bf16x8 a5 = *(const bf16x8*)(hcS_ + oH2);                     \
    const bf16x8 a6 = *(const bf16x8*)(hcS_ + oH2 + 32);                \
    f32x4 A0 = {b0, b0, b0, b0}, A1 = {b1, b1, b1, b1},                 \
          A2 = {b2, b2, b2, b2}, A3 = {b3, b3, b3, b3};                 \
    MFMA_ALL7()                                                         \
    float hv0, hv1, hv2, hv3;                                           \
    ACTK(A0[0], A1[0], A2[0], A3[0], c0, hv0, FRZ);                     \
    ACTK(A0[1], A1[1], A2[1], A3[1], c1, hv1, FRZ);                     \
    ACTK(A0[2], A1[2], A2[2], A3[2], c2, hv2, FRZ);                     \
    ACTK(A0[3], A1[3], A2[3], A3[3], c3, hv3, FRZ);                     \
    short* hd_ = (((SUB) & 1) == 0) ? hw1 : hw0;                        \
    const unsigned pA_ = pkbf(hv0, hv1);                                \
    const unsigned pB_ = pkbf(hv2, hv3);                                \
    hd_[0]   = (short)pA_; hd_[72]  = (short)(pA_ >> 16);               \
    hd_[144] = (short)pB_; hd_[216] = (short)(pB_ >> 16);               \
    if (XST) {                                                          \
        short4v pa_; pa_[0] = f2bf(xr0.x); pa_[1] = f2bf(xr0.y);        \
        pa_[2] = f2bf(xr0.z); pa_[3] = f2bf(xr0.w);                     \
        *(short4v*)(xsW) = pa_;                                         \
        short4v pb_; pb_[0] = f2bf(xr1.x); pb_[1] = f2bf(xr1.y);        \
        pb_[2] = f2bf(xr1.z); pb_[3] = f2bf(xr1.w);                     \
        *(short4v*)(xsW + 16) = pb_;                                    \
    }                                                                   \
    __syncthreads();                                                    \
} while (0)

__global__ __launch_bounds__(256)
void lstm_mfma_68547678044465(const float* __restrict__ x,
                              const float* __restrict__ Wih0, const float* __restrict__ Whh0,
                              const float* __restrict__ bih0, const float* __restrict__ bhh0,
                              const float* __restrict__ Wih1, const float* __restrict__ Whh1,
                              const float* __restrict__ bih1, const float* __restrict__ bhh1,
                              const float* __restrict__ ln_g, const float* __restrict__ ln_b,
                              const float* __restrict__ fcw, const float* __restrict__ fcb,
                              float* __restrict__ out)
{
    __shared__ __align__(16) short XB[2][8][16][40];  // x bf16; rows 8-15 always zero
    __shared__ __align__(16) short HA[2][24][72];     // rows 0-7 zero | 8-15 h0 | 16-23 zero
    __shared__ __align__(16) short HC[2][16][72];     // rows 0-7 zero | 8-15 h1
    __shared__ __align__(16) float HF[8][64];         // final h1 fp32 for LN

    const int tid  = threadIdx.x;
    const int wl   = tid >> 6;           // wave 0..3
    const int lane = tid & 63;
    const int n    = lane & 15;          // A row m / C col n
    const int q    = lane >> 4;          // k-quad / C row group
    const int rb   = blockIdx.x * RPB;
    const int cell = wl * 16 + n;        // h-dim cell 0..63
    const bool qhi = (q >= 2);

    // ---- B-fragments: 4 gate-tiles x 7 K-chunks, named registers ----
    auto loadB = [&](const float* wrow, float sc) -> bf16x8 {
        const float4 lo = *(const float4*)(wrow);
        const float4 hi = *(const float4*)(wrow + 4);
        short8 r;
        r[0] = f2bf(lo.x * sc); r[1] = f2bf(lo.y * sc);
        r[2] = f2bf(lo.z * sc); r[3] = f2bf(lo.w * sc);
        r[4] = f2bf(hi.x * sc); r[5] = f2bf(hi.y * sc);
        r[6] = f2bf(hi.z * sc); r[7] = f2bf(hi.w * sc);
        return (bf16x8)r;
    };
    const int g0 = cell, g1 = 64 + cell, g2 = 128 + cell, g3 = 192 + cell;
    const int ko = q * 8;
    const bf16x8 B0_0 = loadB(Wih0 + g0 * 32 + ko, L2E);
    const bf16x8 B0_1 = loadB(Whh0 + g0 * 64 + ko, L2E);
    const bf16x8 B0_2 = loadB(Whh0 + g0 * 64 + 32 + ko, L2E);
    const bf16x8 B0_3 = loadB(Wih1 + g0 * 64 + ko, L2E);
    const bf16x8 B0_4 = loadB(Wih1 + g0 * 64 + 32 + ko, L2E);
    const bf16x8 B0_5 = loadB(Whh1 + g0 * 64 + ko, L2E);
    const bf16x8 B0_6 = loadB(Whh1 + g0 * 64 + 32 + ko, L2E);
    const bf16x8 B1_0 = loadB(Wih0 + g1 * 32 + ko, L2E);
    const bf16x8 B1_1 = loadB(Whh0 + g1 * 64 + ko, L2E);
    const bf16x8 B1_2 = loadB(Whh0 + g1 * 64 + 32 + ko, L2E);
    const bf16x8 B1_3 = loadB(Wih1 + g1 * 64 + ko, L2E);
    const bf16x8 B1_4 = loadB(Wih1 + g1 * 64 + 32 + ko, L2E);
    const bf16x8 B1_5 = loadB(Whh1 + g1 * 64 + ko, L2E);
    const bf16x8 B1_6 = loadB(Whh1 + g1 * 64 + 32 + ko, L2E);
    const bf16x8 B2_0 = loadB(Wih0 + g2 * 32 + ko, L2E2);
    const bf16x8 B2_1 = loadB(Whh0 + g2 * 64 + ko, L2E2);
    const bf16x8 B2_2 = loadB(Whh0 + g2 * 64 + 32 + ko, L2E2);
    const bf16x8 B2_3 = loadB(Wih1 + g2 * 64 + ko, L2E2);
    const bf16x8 B2_4 = loadB(Wih1 + g2 * 64 + 32 + ko, L2E2);
    const bf16x8 B2_5 = loadB(Whh1 + g2 * 64 + ko, L2E2);
    const bf16x8 B2_6 = loadB(Whh1 + g2 * 64 + 32 + ko, L2E2);
    const bf16x8 B3_0 = loadB(Wih0 + g3 * 32 + ko, L2E);
    const bf16x8 B3_1 = loadB(Whh0 + g3 * 64 + ko, L2E);
    const bf16x8 B3_2 = loadB(Whh0 + g3 * 64 + 32 + ko, L2E);
    const bf16x8 B3_3 = loadB(Wih1 + g3 * 64 + ko, L2E);
    const bf16x8 B3_4 = loadB(Wih1 + g3 * 64 + 32 + ko, L2E);
    const bf16x8 B3_5 = loadB(Whh1 + g3 * 64 + ko, L2E);
    const bf16x8 B3_6 = loadB(Whh1 + g3 * 64 + 32 + ko, L2E);

    // ---- biases: per-lane layer select (q<2 -> L0 rows, q>=2 -> L1 rows) ----
    float b0, b1, b2, b3;
    if (!qhi) {
        b0 = (bih0[g0] + bhh0[g0]) * L2E;  b1 = (bih0[g1] + bhh0[g1]) * L2E;
        b2 = (bih0[g2] + bhh0[g2]) * L2E2; b3 = (bih0[g3] + bhh0[g3]) * L2E;
    } else {
        b0 = (bih1[g0] + bhh1[g0]) * L2E;  b1 = (bih1[g1] + bhh1[g1]) * L2E;
        b2 = (bih1[g2] + bhh1[g2]) * L2E2; b3 = (bih1[g3] + bhh1[g3]) * L2E;
    }

    // ---- zero all LDS (zero rows must stay zero; parity bufs start 0) ----
    { int* z = (int*)XB; for (int i = tid; i < 5120; i += 256) z[i] = 0; }
    { int* z = (int*)HA; for (int i = tid; i < 1728; i += 256) z[i] = 0; }
    { int* z = (int*)HC; for (int i = tid; i < 1152; i += 256) z[i] = 0; }

    // ---- per-lane invariant LDS pointers / offsets ----
    const short* haA = &HA[0][0][0];
    const short* haB = &HA[1][0][0];
    const short* hcA = &HC[0][0][0];
    const short* hcB = &HC[1][0][0];
    const int oH1 = (8 + n) * 72 + q * 8;     // h0 rows 8+m (L0 side)
    const int oH2 = n * 72 + q * 8;           // rows m (zero pad | data)
    const short* xb0 = &XB[0][0][0][0] + (n * 40 + q * 8);
    const short* xb1 = xb0 + 5120;
    short* hw0 = (qhi ? &HC[0][8 + (q & 1) * 4][0]
                      : &HA[0][8 + (q & 1) * 4][0]) + cell;   // parity-0 target
    short* hw1 = (qhi ? &HC[1][8 + (q & 1) * 4][0]
                      : &HA[1][8 + (q & 1) * 4][0]) + cell;   // parity-1 target

    // ---- x staging: thread -> (step ss, row sm, quad kq), 2 float4 each ----
    const int ss = tid >> 5, sm = (tid >> 2) & 7, kq = tid & 3;
    const float* xrow = x + (size_t)(rb + sm) * (TSTEPS * 32);
    short* xs0 = &XB[0][ss][sm][0] + kq * 4;
    short* xs1 = xs0 + 5120;
    const float* xp = xrow + (8 + ss) * 32 + kq * 4;   // group-1 prefetch base
    float4 xr0 = *(const float4*)(xrow + ss * 32 + kq * 4);
    float4 xr1 = *(const float4*)(xrow + ss * 32 + kq * 4 + 16);
    {   // initial stage of group 0 into buf 0
        short4v pa; pa[0] = f2bf(xr0.x); pa[1] = f2bf(xr0.y);
        pa[2] = f2bf(xr0.z); pa[3] = f2bf(xr0.w);
        *(short4v*)(xs0) = pa;
        short4v pb; pb[0] = f2bf(xr1.x); pb[1] = f2bf(xr1.y);
        pb[2] = f2bf(xr1.z); pb[3] = f2bf(xr1.w);
        *(short4v*)(xs0 + 16) = pb;
    }
    __syncthreads();

    float c0 = 0.0f, c1 = 0.0f, c2 = 0.0f, c3 = 0.0f;

#pragma unroll 1
    for (int g = 0; g < 64; ++g) {
        const short* xbR = (g & 1) ? xb1 : xb0;   // read buf = g&1
        short* xsW       = (g & 1) ? xs0 : xs1;   // stage target = (g+1)&1
        const bool fz = (g == 0) && qhi;          // phantom L1 step -1
        const bool pg = (g < 63);
        STEPB(0, pg, 0, fz);
        STEPB(1, 0, 0, false);
        STEPB(2, 0, 0, false);
        STEPB(3, 0, 0, false);
        STEPB(4, 0, 0, false);
        STEPB(5, 0, 0, false);
        STEPB(6, 0, pg, false);
        STEPB(7, 0, 0, false);
        xp += 256;                                // next group's prefetch base
    }

    // ---- peeled epilogue step (it = TSTEPS): only L1 (q>=2) results used.
    // Rows 0-7 read stale XB data (finite garbage) -> L0 lanes' values unused.
    {
        const bf16x8 a0 = *(const bf16x8*)(xb0);
        const bf16x8 a1 = *(const bf16x8*)(haA + oH1);
        const bf16x8 a2 = *(const bf16x8*)(haA + oH1 + 32);
        const bf16x8 a3 = *(const bf16x8*)(haA + oH2);
        const bf16x8 a4 = *(const bf16x8*)(haA + oH2 + 32);
        const bf16x8 a5 = *(const bf16x8*)(hcA + oH2);
        const bf16x8 a6 = *(const bf16x8*)(hcA + oH2 + 32);
        f32x4 A0 = {b0, b0, b0, b0}, A1 = {b1, b1, b1, b1},
              A2 = {b2, b2, b2, b2}, A3 = {b3, b3, b3, b3};
        MFMA_ALL7()
        float hv0, hv1, hv2, hv3;
        ACTK(A0[0], A1[0], A2[0], A3[0], c0, hv0, false);
        ACTK(A0[1], A1[1], A2[1], A3[1], c1, hv1, false);
        ACTK(A0[2], A1[2], A2[2], A3[2], c2, hv2, false);
        ACTK(A0[3], A1[3], A2[3], A3[3], c3, hv3, false);
        if (qhi) {                              // final h1 (step T-1), fp32
            const int rl = (q & 1) * 4;
            HF[rl + 0][cell] = hv0;
            HF[rl + 1][cell] = hv1;
            HF[rl + 2][cell] = hv2;
            HF[rl + 3][cell] = hv3;
        }
    }
    __syncthreads();

    // ---- epilogue: LayerNorm + FC; each wave handles 2 rows ----
    const float lg = ln_g[lane], lb = ln_b[lane], fw = fcw[lane], fb = fcb[0];
#pragma unroll
    for (int rr = 0; rr < 2; ++rr) {
        const int row = wl * 2 + rr;
        const float v = HF[row][lane];
        float s1 = v, sq = v * v;
#pragma unroll
        for (int mm = 1; mm < 64; mm <<= 1) {
            s1 += __shfl_xor(s1, mm, 64);
            sq += __shfl_xor(sq, mm, 64);
        }
        const float mu = s1 * (1.0f / 64.0f);
        float var = sq * (1.0f / 64.0f) - mu * mu;
        var = fmaxf(var, 0.0f);
        const float rs = rsqrtf(var + 1e-5f);
        float pv = ((v - mu) * rs * lg + lb) * fw;
#pragma unroll
        for (int mm = 1; mm < 64; mm <<= 1) pv += __shfl_xor(pv, mm, 64);
        if (lane == 0) out[rb + row] = pv + fb;
    }
}

extern "C" void kernel_launch(void* const* d_in, const int* in_sizes, int n_in,
                              void* d_out, int out_size, void* d_ws, size_t ws_size,
                              hipStream_t stream) {
    const float* x    = (const float*)d_in[0];
    const float* Wih0 = (const float*)d_in[1];
    const float* Whh0 = (const float*)d_in[2];
    const float* bih0 = (const float*)d_in[3];
    const float* bhh0 = (const float*)d_in[4];
    const float* Wih1 = (const float*)d_in[5];
    const float* Whh1 = (const float*)d_in[6];
    const float* bih1 = (const float*)d_in[7];
    const float* bhh1 = (const float*)d_in[8];
    const float* ln_g = (const float*)d_in[9];
    const float* ln_b = (const float*)d_in[10];
    const float* fcw  = (const float*)d_in[11];
    const float* fcb  = (const float*)d_in[12];

    dim3 grid(2048 / RPB);    // 256 blocks -> 1 per CU
    dim3 block(256);          // 4 waves: 1 per SIMD
    hipLaunchKernelGGL(lstm_mfma_68547678044465, grid, block, 0, stream,
                       x, Wih0, Whh0, bih0, bhh0, Wih1, Whh1, bih1, bhh1,
                       ln_g, ln_b, fcw, fcb, (float*)d_out);
}